// Round 1
// baseline (32215.536 us; speedup 1.0000x reference)
//
#include <hip/hip_runtime.h>
#include <hip/hip_bf16.h>
#include <math.h>

// Problem config (fixed)
#define BB 32      // batch
#define TT 128     // time steps
#define UU 1024    // units
#define HH 16      // heads
#define DHD 64     // per-head
#define MM 8       // memory slots
#define LL 9       // M+1
#define RR 17      // 2M+1

// ---------------- generic tiled fp32 GEMM ----------------
// C[M,N] = A[M,K] @ B[K,N] + bias, row-major. lda=K. K%16==0, N%64==0.
#define BM 64
#define BN 64
#define BKK 16

__device__ __forceinline__ void gemm_body(
    const float* __restrict__ A, const float* __restrict__ B,
    const float* __restrict__ bias, float* __restrict__ C,
    int M, int N, int K, int lda, int ldb, int ldc, int act,
    int rowTile, int colTile)
{
    __shared__ float As[BKK][BM + 1];
    __shared__ float Bs[BKK][BN];
    int tid = threadIdx.x;              // 0..255
    int row0 = rowTile * BM, col0 = colTile * BN;
    int ty = tid >> 4, tx = tid & 15;
    float acc[4][4];
#pragma unroll
    for (int i = 0; i < 4; ++i)
#pragma unroll
        for (int j = 0; j < 4; ++j) acc[i][j] = 0.f;

    for (int k0 = 0; k0 < K; k0 += BKK) {
        // A tile: 64 rows x 16 k  (one float4 per thread)
        {
            int r = tid >> 2;
            int kv = (tid & 3) * 4;
            float4 v = make_float4(0.f, 0.f, 0.f, 0.f);
            int gr = row0 + r;
            if (gr < M) v = *(const float4*)(A + (size_t)gr * lda + k0 + kv);
            As[kv + 0][r] = v.x; As[kv + 1][r] = v.y;
            As[kv + 2][r] = v.z; As[kv + 3][r] = v.w;
        }
        // B tile: 16 k x 64 cols (one float4 per thread)
        {
            int r = tid >> 4;
            int cv = (tid & 15) * 4;
            float4 v = *(const float4*)(B + (size_t)(k0 + r) * ldb + col0 + cv);
            *(float4*)&Bs[r][cv] = v;
        }
        __syncthreads();
#pragma unroll
        for (int kk = 0; kk < BKK; ++kk) {
            float a[4], b[4];
#pragma unroll
            for (int j = 0; j < 4; ++j) a[j] = As[kk][ty * 4 + j];
#pragma unroll
            for (int j = 0; j < 4; ++j) b[j] = Bs[kk][tx * 4 + j];
#pragma unroll
            for (int i = 0; i < 4; ++i)
#pragma unroll
                for (int j = 0; j < 4; ++j) acc[i][j] += a[i] * b[j];
        }
        __syncthreads();
    }
#pragma unroll
    for (int i = 0; i < 4; ++i) {
        int gr = row0 + ty * 4 + i;
        if (gr >= M) continue;
#pragma unroll
        for (int j = 0; j < 4; ++j) {
            int gc = col0 + tx * 4 + j;
            float v = acc[i][j];
            if (bias) v += bias[gc];
            if (act == 1) {  // gelu (tanh approx, JAX default)
                float x = v;
                float t = tanhf(0.7978845608028654f * (x + 0.044715f * x * x * x));
                v = 0.5f * x * (1.f + t);
            }
            C[(size_t)gr * ldc + gc] = v;
        }
    }
}

__global__ __launch_bounds__(256) void gemm_f32(
    const float* __restrict__ A, const float* __restrict__ B,
    const float* __restrict__ bias, float* __restrict__ C,
    int M, int N, int K, int ldb, int ldc, int act)
{
    gemm_body(A, B, bias, C, M, N, K, K, ldb, ldc, act, blockIdx.y, blockIdx.x);
}

// fused per-step GEMM: qkv[288,3072] and grec[288,2048] from mp[288,1024]
__global__ __launch_bounds__(256) void gemm_qkvg(
    const float* __restrict__ mp,
    const float* __restrict__ Wa, const float* __restrict__ ba,
    const float* __restrict__ Wr, const float* __restrict__ br,
    float* __restrict__ qkv, float* __restrict__ grec)
{
    int ct = blockIdx.x;  // 0..79
    if (ct < 48)
        gemm_body(mp, Wa, ba, qkv, BB * LL, 3072, UU, UU, 3072, 3072, 0, blockIdx.y, ct);
    else
        gemm_body(mp, Wr, br, grec, BB * LL, 2048, UU, UU, 2048, 2048, 0, blockIdx.y, ct - 48);
}

// ---------------- relative embedding table ----------------
__global__ void relemb_kernel(float* __restrict__ tab)
{
    int p = blockIdx.x;                   // 0..16
    float pv = (float)(p - MM);
    for (int i = threadIdx.x; i < UU; i += blockDim.x) {
        float expo = (float)(i & ~1) * (1.0f / (float)UU);
        // 10000^(-expo) = 2^(-expo*log2(10000))
        float scale = exp2f(-expo * 13.287712379549449f);
        float ang = pv * scale;
        tab[p * UU + i] = (i & 1) ? cosf(ang) : sinf(ang);
    }
}

// ---------------- init mp ----------------
__global__ void init_mp(const float* __restrict__ xp_all, float* __restrict__ mp)
{
    int row = blockIdx.x;                 // 0..287
    int b = row / LL, l = row % LL;
    for (int u = threadIdx.x; u < UU; u += blockDim.x)
        mp[(size_t)row * UU + u] = (l == MM) ? xp_all[((size_t)b * TT) * UU + u] : 0.f;
}

// ---------------- attention + LN1 (one block per batch element) ----------------
__global__ __launch_bounds__(512) void attn_ln(
    const float* __restrict__ qkv, const float* __restrict__ rproj,
    const float* __restrict__ mp,
    const float* __restrict__ gamma, const float* __restrict__ beta,
    float* __restrict__ a1)
{
    __shared__ float sA[LL][UU];
    __shared__ float red[16];
    int b = blockIdx.x;
    int tid = threadIdx.x;
    int wave = tid >> 6, lane = tid & 63;

    for (int hh = 0; hh < 2; ++hh) {
        int h = wave + hh * 8;
        const float* base = qkv + (size_t)b * LL * 3072 + h * DHD + lane;
        float q[LL], k[LL], v[LL], r[RR];
#pragma unroll
        for (int l = 0; l < LL; ++l) {
            q[l] = base[l * 3072];
            k[l] = base[l * 3072 + 1024];
            v[l] = base[l * 3072 + 2048];
        }
#pragma unroll
        for (int rp = 0; rp < RR; ++rp) r[rp] = rproj[rp * UU + h * DHD + lane];
#pragma unroll
        for (int qr = 0; qr < LL; ++qr) {
            float sc[LL];
#pragma unroll
            for (int kr = 0; kr < LL; ++kr) {
                float prod = q[qr] * (k[kr] + r[qr - kr + MM]);
#pragma unroll
                for (int o = 32; o > 0; o >>= 1) prod += __shfl_xor(prod, o);
                sc[kr] = prod * 0.125f;
            }
            float m = sc[0];
#pragma unroll
            for (int kr = 1; kr < LL; ++kr) m = fmaxf(m, sc[kr]);
            float s = 0.f;
#pragma unroll
            for (int kr = 0; kr < LL; ++kr) { sc[kr] = expf(sc[kr] - m); s += sc[kr]; }
            float inv = 1.0f / s;
            float acc = 0.f;
#pragma unroll
            for (int kr = 0; kr < LL; ++kr) acc += sc[kr] * v[kr];
            sA[qr][h * DHD + lane] = acc * inv;
        }
    }
    __syncthreads();

    // LayerNorm over each of the 9 rows: a1 = LN(mp + attn)
    for (int l = 0; l < LL; ++l) {
        size_t row = (size_t)(b * LL + l);
        float x0 = mp[row * UU + tid] + sA[l][tid];
        float x1 = mp[row * UU + tid + 512] + sA[l][tid + 512];
        float s = x0 + x1, ss = x0 * x0 + x1 * x1;
#pragma unroll
        for (int o = 32; o > 0; o >>= 1) { s += __shfl_xor(s, o); ss += __shfl_xor(ss, o); }
        if (lane == 0) { red[wave * 2] = s; red[wave * 2 + 1] = ss; }
        __syncthreads();
        float S = 0.f, SS = 0.f;
#pragma unroll
        for (int w = 0; w < 8; ++w) { S += red[w * 2]; SS += red[w * 2 + 1]; }
        __syncthreads();
        float mean = S * (1.0f / UU);
        float var = SS * (1.0f / UU) - mean * mean;
        float rstd = rsqrtf(var + 1e-6f);
        a1[row * UU + tid]       = (x0 - mean) * rstd * gamma[tid] + beta[tid];
        a1[row * UU + tid + 512] = (x1 - mean) * rstd * gamma[tid + 512] + beta[tid + 512];
    }
}

// ---------------- finalize: LN2 + gates + memory update + output ----------------
__global__ __launch_bounds__(256) void finalize_step(
    const float* __restrict__ a1, const float* __restrict__ m2,
    const float* __restrict__ grec, const float* __restrict__ gx_all,
    const float* __restrict__ xp_all,
    const float* __restrict__ gamma, const float* __restrict__ beta,
    float* __restrict__ mp, float* __restrict__ out, int t)
{
    __shared__ float red[8];
    int row = blockIdx.x;                 // 0..287
    int b = row / LL, l = row % LL;
    int tid = threadIdx.x;
    int wave = tid >> 6, lane = tid & 63;

    float x[4];
    float s = 0.f, ss = 0.f;
#pragma unroll
    for (int j = 0; j < 4; ++j) {
        int u = tid + j * 256;
        x[j] = a1[(size_t)row * UU + u] + m2[(size_t)row * UU + u];
        s += x[j]; ss += x[j] * x[j];
    }
#pragma unroll
    for (int o = 32; o > 0; o >>= 1) { s += __shfl_xor(s, o); ss += __shfl_xor(ss, o); }
    if (lane == 0) { red[wave * 2] = s; red[wave * 2 + 1] = ss; }
    __syncthreads();
    float S = 0.f, SS = 0.f;
#pragma unroll
    for (int w = 0; w < 4; ++w) { S += red[w * 2]; SS += red[w * 2 + 1]; }
    float mean = S * (1.0f / UU);
    float rstd = rsqrtf(SS * (1.0f / UU) - mean * mean + 1e-6f);

    size_t gxoff = ((size_t)b * TT + t) * 2048;
#pragma unroll
    for (int j = 0; j < 4; ++j) {
        int u = tid + j * 256;
        float cand = (x[j] - mean) * rstd * gamma[1024 + u] + beta[1024 + u];
        float tc = tanhf(cand);
        float gi = gx_all[gxoff + u]        + grec[(size_t)row * 2048 + u];
        float gf = gx_all[gxoff + 1024 + u] + grec[(size_t)row * 2048 + 1024 + u];
        float ig = fminf(fmaxf(0.2f * gi + 0.5f, 0.f), 1.f);
        float fg = fminf(fmaxf(0.2f * (gf + 1.0f) + 0.5f, 0.f), 1.f);
        float nmp = fg * mp[(size_t)row * UU + u] + ig * tc;
        if (l < MM) {
            mp[(size_t)row * UU + u] = nmp;
        } else {
            out[((size_t)b * TT + t) * UU + u] = nmp;
            if (t + 1 < TT)
                mp[(size_t)row * UU + u] = xp_all[((size_t)b * TT + t + 1) * UU + u];
        }
    }
}

// ---------------- host launcher ----------------
extern "C" void kernel_launch(void* const* d_in, const int* in_sizes, int n_in,
                              void* d_out, int out_size, void* d_ws, size_t ws_size,
                              hipStream_t stream)
{
    const float* x        = (const float*)d_in[0];   // [32,128,1024]
    const float* Wi       = (const float*)d_in[1];   // [1024,1024]
    const float* bi       = (const float*)d_in[2];   // [1024]
    const float* Wg       = (const float*)d_in[3];   // [1024,2048]
    const float* Wr       = (const float*)d_in[4];   // [1024,2048]
    const float* br       = (const float*)d_in[5];   // [2048]
    const float* Wa       = (const float*)d_in[6];   // [1024,3072]
    const float* ba       = (const float*)d_in[7];   // [3072]
    const float* Wm       = (const float*)d_in[8];   // [1024,2048]
    const float* bm       = (const float*)d_in[9];   // [2048]
    const float* gam      = (const float*)d_in[10];  // [2048]
    const float* bet      = (const float*)d_in[11];  // [2048]
    const float* Wrel     = (const float*)d_in[12];  // [1024,1024]
    float* out = (float*)d_out;

    float* ws = (float*)d_ws;
    size_t XP   = 0;                          // [32,128,1024]
    size_t GX   = XP + (size_t)BB * TT * UU;  // [32,128,2048]
    size_t TAB  = GX + (size_t)BB * TT * 2048;        // [17,1024]
    size_t RP   = TAB + (size_t)RR * UU;              // [17,1024]
    size_t MP   = RP + (size_t)RR * UU;               // [288,1024]
    size_t QKV  = MP + (size_t)BB * LL * UU;          // [288,3072]
    size_t GREC = QKV + (size_t)BB * LL * 3072;       // [288,2048]
    size_t A1   = GREC + (size_t)BB * LL * 2048;      // [288,1024]
    size_t HH_  = A1 + (size_t)BB * LL * UU;          // [288,1024]
    size_t M2   = HH_ + (size_t)BB * LL * UU;         // [288,1024]

    float* xp_all = ws + XP;
    float* gx_all = ws + GX;
    float* tab    = ws + TAB;
    float* rproj  = ws + RP;
    float* mp     = ws + MP;
    float* qkv    = ws + QKV;
    float* grec   = ws + GREC;
    float* a1     = ws + A1;
    float* h      = ws + HH_;
    float* m2     = ws + M2;

    // ---- up-front (non-recurrent) work ----
    relemb_kernel<<<RR, 256, 0, stream>>>(tab);
    // rproj[17,1024] = tab @ Wrel
    gemm_f32<<<dim3(UU / BN, 1), 256, 0, stream>>>(tab, Wrel, nullptr, rproj,
                                                   RR, UU, UU, UU, UU, 0);
    // xp_all[4096,1024] = x @ Wi + bi
    gemm_f32<<<dim3(UU / BN, (BB * TT) / BM), 256, 0, stream>>>(
        x, Wi, bi, xp_all, BB * TT, UU, UU, UU, UU, 0);
    // gx_all[4096,2048] = x @ Wg
    gemm_f32<<<dim3(2048 / BN, (BB * TT) / BM), 256, 0, stream>>>(
        x, Wg, nullptr, gx_all, BB * TT, 2048, UU, 2048, 2048, 0);
    init_mp<<<BB * LL, 256, 0, stream>>>(xp_all, mp);

    // ---- sequential scan ----
    for (int t = 0; t < TT; ++t) {
        // qkv + grec from mp
        gemm_qkvg<<<dim3(80, 5), 256, 0, stream>>>(mp, Wa, ba, Wr, br, qkv, grec);
        // attention + LN1 -> a1
        attn_ln<<<BB, 512, 0, stream>>>(qkv, rproj, mp, gam, bet, a1);
        // h = gelu(a1 @ Wm[:, :U] + bm[:U])
        gemm_f32<<<dim3(UU / BN, 5), 256, 0, stream>>>(a1, Wm, bm, h,
                                                       BB * LL, UU, UU, 2048, UU, 1);
        // m2 = h @ Wm[:, U:] + bm[U:]
        gemm_f32<<<dim3(UU / BN, 5), 256, 0, stream>>>(h, Wm + 1024, bm + 1024, m2,
                                                       BB * LL, UU, UU, 2048, UU, 0);
        // LN2 + gates + memory update + y_t
        finalize_step<<<BB * LL, 256, 0, stream>>>(a1, m2, grec, gx_all, xp_all,
                                                   gam, bet, mp, out, t);
    }
}

// Round 3
// 29403.271 us; speedup vs baseline: 1.0956x; 1.0956x over previous
//
#include <hip/hip_runtime.h>
#include <hip/hip_bf16.h>
#include <math.h>

// Problem config (fixed)
#define BB 32      // batch
#define TT 128     // time steps
#define UU 1024    // units
#define MM 8       // memory slots
#define LL 9       // M+1
#define RR 17      // 2M+1

// ---------------- big fp32 GEMM body: 64x128 tile, K-step 64 ----------------
// C tile at (row0, colC), B cols at colB (B has leading dim ldb).
// Per-output strict ascending-k accumulation (bit-stable vs R0).
__device__ __forceinline__ void gbody(
    const float* __restrict__ A, const float* __restrict__ B,
    const float* __restrict__ bias, float* __restrict__ C,
    int M, int K, int ldb, int ldc, int act,
    int row0, int colB, int colC)
{
    __shared__ float As[64][68];   // [m][k], padded
    __shared__ float Bs[64][128];  // [k][n]
    int tid = threadIdx.x;
    int ty = tid >> 5, tx = tid & 31;   // ty 0..7 (8 rows each), tx 0..31 (4 cols each)
    float acc[8][4];
#pragma unroll
    for (int i = 0; i < 8; ++i)
#pragma unroll
        for (int j = 0; j < 4; ++j) acc[i][j] = 0.f;

    for (int k0 = 0; k0 < K; k0 += 64) {
        // A tile 64 rows x 64 k: coalesced float4 along k
#pragma unroll
        for (int p = 0; p < 4; ++p) {
            int r = p * 16 + (tid >> 4);
            int kv = (tid & 15) * 4;
            int gr = row0 + r;
            float4 v = make_float4(0.f, 0.f, 0.f, 0.f);
            if (gr < M) v = *(const float4*)(A + (size_t)gr * K + k0 + kv);
            *(float4*)&As[r][kv] = v;
        }
        // B tile 64 k x 128 n: coalesced float4 along n
#pragma unroll
        for (int p = 0; p < 8; ++p) {
            int r = p * 8 + (tid >> 5);
            int c = (tid & 31) * 4;
            *(float4*)&Bs[r][c] = *(const float4*)(B + (size_t)(k0 + r) * ldb + colB + c);
        }
        __syncthreads();
#pragma unroll 8
        for (int kk = 0; kk < 64; ++kk) {
            float b0[4];
            *(float4*)b0 = *(const float4*)&Bs[kk][tx * 4];
            float a0[8];
#pragma unroll
            for (int i = 0; i < 8; ++i) a0[i] = As[ty * 8 + i][kk];  // broadcast reads
#pragma unroll
            for (int i = 0; i < 8; ++i)
#pragma unroll
                for (int j = 0; j < 4; ++j) acc[i][j] += a0[i] * b0[j];
        }
        __syncthreads();
    }

    int cc = colC + tx * 4;
#pragma unroll
    for (int i = 0; i < 8; ++i) {
        int gr = row0 + ty * 8 + i;
        if (gr >= M) continue;
#pragma unroll
        for (int j = 0; j < 4; ++j) {
            float v = acc[i][j];
            if (bias) v += bias[colB + tx * 4 + j];
            if (act == 1) {  // gelu (tanh approx, JAX default)
                float x = v;
                float t = tanhf(0.7978845608028654f * (x + 0.044715f * x * x * x));
                v = 0.5f * x * (1.f + t);
            }
            C[(size_t)gr * ldc + cc + j] = v;
        }
    }
}

// generic: C[M,N] = A[M,K]@B[K,N] (+bias,+act), ldb=ldc=N. grid (N/128, ceil(M/64))
__global__ __launch_bounds__(256) void gemm_big(
    const float* __restrict__ A, const float* __restrict__ B,
    const float* __restrict__ bias, float* __restrict__ C,
    int M, int N, int K, int act)
{
    gbody(A, B, bias, C, M, K, N, N, act, blockIdx.y * 64, blockIdx.x * 128,
          blockIdx.x * 128);
}

// fused per-step: qkvg[288,5120] = mp @ [Wa | Wr] + [ba | br]. grid (40, 5)
__global__ __launch_bounds__(256) void gemm_qkvg(
    const float* __restrict__ mp,
    const float* __restrict__ Wa, const float* __restrict__ ba,
    const float* __restrict__ Wr, const float* __restrict__ br,
    float* __restrict__ qkvg)
{
    int bx = blockIdx.x;
    if (bx < 24)
        gbody(mp, Wa, ba, qkvg, BB * LL, UU, 3072, 5120, 0,
              blockIdx.y * 64, bx * 128, bx * 128);
    else
        gbody(mp, Wr, br, qkvg, BB * LL, UU, 2048, 5120, 0,
              blockIdx.y * 64, (bx - 24) * 128, bx * 128);
}

// ---------------- small fp32 GEMM: 32x64 tile, K-step 64 ----------------
// grid (N/64, M/32). ldb for strided weight slices, ldc = N.
__global__ __launch_bounds__(256) void gemm_small(
    const float* __restrict__ A, const float* __restrict__ B,
    const float* __restrict__ bias, float* __restrict__ C,
    int M, int N, int K, int ldb, int act)
{
    __shared__ float As[32][68];
    __shared__ float Bs[64][64];
    int tid = threadIdx.x;
    int row0 = blockIdx.y * 32, col0 = blockIdx.x * 64;
    int ty = tid >> 4, tx = tid & 15;   // ty 0..15 (2 rows each), tx 0..15 (4 cols)
    float acc[2][4];
#pragma unroll
    for (int i = 0; i < 2; ++i)
#pragma unroll
        for (int j = 0; j < 4; ++j) acc[i][j] = 0.f;

    for (int k0 = 0; k0 < K; k0 += 64) {
#pragma unroll
        for (int p = 0; p < 2; ++p) {
            int r = p * 16 + (tid >> 4);
            int kv = (tid & 15) * 4;
            int gr = row0 + r;
            float4 v = make_float4(0.f, 0.f, 0.f, 0.f);
            if (gr < M) v = *(const float4*)(A + (size_t)gr * K + k0 + kv);
            *(float4*)&As[r][kv] = v;
        }
#pragma unroll
        for (int p = 0; p < 4; ++p) {
            int r = p * 16 + (tid >> 4);
            int c = (tid & 15) * 4;
            *(float4*)&Bs[r][c] = *(const float4*)(B + (size_t)(k0 + r) * ldb + col0 + c);
        }
        __syncthreads();
#pragma unroll 8
        for (int kk = 0; kk < 64; ++kk) {
            float b0[4];
            *(float4*)b0 = *(const float4*)&Bs[kk][tx * 4];
            float a0 = As[ty * 2 + 0][kk];
            float a1v = As[ty * 2 + 1][kk];
#pragma unroll
            for (int j = 0; j < 4; ++j) acc[0][j] += a0 * b0[j];
#pragma unroll
            for (int j = 0; j < 4; ++j) acc[1][j] += a1v * b0[j];
        }
        __syncthreads();
    }

#pragma unroll
    for (int i = 0; i < 2; ++i) {
        int gr = row0 + ty * 2 + i;
        if (gr >= M) continue;
#pragma unroll
        for (int j = 0; j < 4; ++j) {
            float v = acc[i][j];
            int col = col0 + tx * 4 + j;
            if (bias) v += bias[col];
            if (act == 1) {
                float x = v;
                float t = tanhf(0.7978845608028654f * (x + 0.044715f * x * x * x));
                v = 0.5f * x * (1.f + t);
            }
            C[(size_t)gr * N + col] = v;
        }
    }
}

// ---------------- fp32 fallback GEMM (tiny one-time rproj) ----------------
#define BM 64
#define BN 64
#define BKK 16
__global__ __launch_bounds__(256) void gemm_f32(
    const float* __restrict__ A, const float* __restrict__ B,
    float* __restrict__ C, int M, int N, int K)
{
    __shared__ float As[BKK][BM + 1];
    __shared__ float Bs[BKK][BN];
    int tid = threadIdx.x;
    int row0 = blockIdx.y * BM, col0 = blockIdx.x * BN;
    int ty = tid >> 4, tx = tid & 15;
    float acc[4][4];
#pragma unroll
    for (int i = 0; i < 4; ++i)
#pragma unroll
        for (int j = 0; j < 4; ++j) acc[i][j] = 0.f;
    for (int k0 = 0; k0 < K; k0 += BKK) {
        {
            int r = tid >> 2, kv = (tid & 3) * 4;
            float4 v = make_float4(0.f, 0.f, 0.f, 0.f);
            int gr = row0 + r;
            if (gr < M) v = *(const float4*)(A + (size_t)gr * K + k0 + kv);
            As[kv + 0][r] = v.x; As[kv + 1][r] = v.y;
            As[kv + 2][r] = v.z; As[kv + 3][r] = v.w;
        }
        {
            int r = tid >> 4, cv = (tid & 15) * 4;
            float4 v = *(const float4*)(B + (size_t)(k0 + r) * N + col0 + cv);
            *(float4*)&Bs[r][cv] = v;
        }
        __syncthreads();
#pragma unroll
        for (int kk = 0; kk < BKK; ++kk) {
            float a[4], b[4];
#pragma unroll
            for (int j = 0; j < 4; ++j) a[j] = As[kk][ty * 4 + j];
#pragma unroll
            for (int j = 0; j < 4; ++j) b[j] = Bs[kk][tx * 4 + j];
#pragma unroll
            for (int i = 0; i < 4; ++i)
#pragma unroll
                for (int j = 0; j < 4; ++j) acc[i][j] += a[i] * b[j];
        }
        __syncthreads();
    }
#pragma unroll
    for (int i = 0; i < 4; ++i) {
        int gr = row0 + ty * 4 + i;
        if (gr >= M) continue;
#pragma unroll
        for (int j = 0; j < 4; ++j)
            C[(size_t)gr * N + col0 + tx * 4 + j] = acc[i][j];
    }
}

// ---------------- relative embedding table ----------------
__global__ void relemb_kernel(float* __restrict__ tab)
{
    int p = blockIdx.x;                   // 0..16
    float pv = (float)(p - MM);
    for (int i = threadIdx.x; i < UU; i += blockDim.x) {
        float expo = (float)(i & ~1) * (1.0f / (float)UU);
        float scale = exp2f(-expo * 13.287712379549449f);  // 10000^-expo
        float ang = pv * scale;
        tab[p * UU + i] = (i & 1) ? cosf(ang) : sinf(ang);
    }
}

// ---------------- init mp ----------------
__global__ void init_mp(const float* __restrict__ xp_all, float* __restrict__ mp)
{
    int row = blockIdx.x;                 // 0..287
    int b = row / LL, l = row % LL;
    for (int u = threadIdx.x; u < UU; u += blockDim.x)
        mp[(size_t)row * UU + u] = (l == MM) ? xp_all[((size_t)b * TT) * UU + u] : 0.f;
}

// ---------------- attention + LN1 (one block per batch element) ----------------
__global__ __launch_bounds__(512) void attn_ln(
    const float* __restrict__ qkvg, const float* __restrict__ rproj,
    const float* __restrict__ mp,
    const float* __restrict__ gamma, const float* __restrict__ beta,
    float* __restrict__ a1)
{
    __shared__ float sA[LL][UU];
    __shared__ float red[16];
    int b = blockIdx.x;
    int tid = threadIdx.x;
    int wave = tid >> 6, lane = tid & 63;

    for (int hh = 0; hh < 2; ++hh) {
        int h = wave + hh * 8;
        const float* base = qkvg + (size_t)b * LL * 5120 + h * 64 + lane;
        float q[LL], k[LL], v[LL], r[RR];
#pragma unroll
        for (int l = 0; l < LL; ++l) {
            q[l] = base[l * 5120];
            k[l] = base[l * 5120 + 1024];
            v[l] = base[l * 5120 + 2048];
        }
#pragma unroll
        for (int rp = 0; rp < RR; ++rp) r[rp] = rproj[rp * UU + h * 64 + lane];
#pragma unroll
        for (int qr = 0; qr < LL; ++qr) {
            float sc[LL];
#pragma unroll
            for (int kr = 0; kr < LL; ++kr) {
                float prod = q[qr] * (k[kr] + r[qr - kr + MM]);
#pragma unroll
                for (int o = 32; o > 0; o >>= 1) prod += __shfl_xor(prod, o);
                sc[kr] = prod * 0.125f;
            }
            float m = sc[0];
#pragma unroll
            for (int kr = 1; kr < LL; ++kr) m = fmaxf(m, sc[kr]);
            float s = 0.f;
#pragma unroll
            for (int kr = 0; kr < LL; ++kr) { sc[kr] = expf(sc[kr] - m); s += sc[kr]; }
            float inv = 1.0f / s;
            float acc = 0.f;
#pragma unroll
            for (int kr = 0; kr < LL; ++kr) acc += sc[kr] * v[kr];
            sA[qr][h * 64 + lane] = acc * inv;
        }
    }
    __syncthreads();

    for (int l = 0; l < LL; ++l) {
        size_t row = (size_t)(b * LL + l);
        float x0 = mp[row * UU + tid] + sA[l][tid];
        float x1 = mp[row * UU + tid + 512] + sA[l][tid + 512];
        float s = x0 + x1, ss = x0 * x0 + x1 * x1;
#pragma unroll
        for (int o = 32; o > 0; o >>= 1) { s += __shfl_xor(s, o); ss += __shfl_xor(ss, o); }
        if (lane == 0) { red[wave * 2] = s; red[wave * 2 + 1] = ss; }
        __syncthreads();
        float S = 0.f, SS = 0.f;
#pragma unroll
        for (int w = 0; w < 8; ++w) { S += red[w * 2]; SS += red[w * 2 + 1]; }
        __syncthreads();
        float mean = S * (1.0f / UU);
        float var = SS * (1.0f / UU) - mean * mean;
        float rstd = rsqrtf(var + 1e-6f);
        a1[row * UU + tid]       = (x0 - mean) * rstd * gamma[tid] + beta[tid];
        a1[row * UU + tid + 512] = (x1 - mean) * rstd * gamma[tid + 512] + beta[tid + 512];
    }
}

// ---------------- finalize: LN2 + gates + memory update + output ----------------
__global__ __launch_bounds__(256) void finalize_step(
    const float* __restrict__ a1, const float* __restrict__ m2,
    const float* __restrict__ qkvg, const float* __restrict__ gx_all,
    const float* __restrict__ xp_all,
    const float* __restrict__ gamma, const float* __restrict__ beta,
    float* __restrict__ mp, float* __restrict__ out, int t)
{
    __shared__ float red[8];
    int row = blockIdx.x;                 // 0..287
    int b = row / LL, l = row % LL;
    int tid = threadIdx.x;
    int wave = tid >> 6, lane = tid & 63;

    float x[4];
    float s = 0.f, ss = 0.f;
#pragma unroll
    for (int j = 0; j < 4; ++j) {
        int u = tid + j * 256;
        x[j] = a1[(size_t)row * UU + u] + m2[(size_t)row * UU + u];
        s += x[j]; ss += x[j] * x[j];
    }
#pragma unroll
    for (int o = 32; o > 0; o >>= 1) { s += __shfl_xor(s, o); ss += __shfl_xor(ss, o); }
    if (lane == 0) { red[wave * 2] = s; red[wave * 2 + 1] = ss; }
    __syncthreads();
    float S = 0.f, SS = 0.f;
#pragma unroll
    for (int w = 0; w < 4; ++w) { S += red[w * 2]; SS += red[w * 2 + 1]; }
    float mean = S * (1.0f / UU);
    float rstd = rsqrtf(SS * (1.0f / UU) - mean * mean + 1e-6f);

    size_t gxoff = ((size_t)b * TT + t) * 2048;
    size_t grow = (size_t)row * 5120 + 3072;
#pragma unroll
    for (int j = 0; j < 4; ++j) {
        int u = tid + j * 256;
        float cand = (x[j] - mean) * rstd * gamma[1024 + u] + beta[1024 + u];
        float tc = tanhf(cand);
        float gi = gx_all[gxoff + u]        + qkvg[grow + u];
        float gf = gx_all[gxoff + 1024 + u] + qkvg[grow + 1024 + u];
        float ig = fminf(fmaxf(0.2f * gi + 0.5f, 0.f), 1.f);
        float fg = fminf(fmaxf(0.2f * (gf + 1.0f) + 0.5f, 0.f), 1.f);
        float nmp = fg * mp[(size_t)row * UU + u] + ig * tc;
        if (l < MM) {
            mp[(size_t)row * UU + u] = nmp;
        } else {
            out[((size_t)b * TT + t) * UU + u] = nmp;
            if (t + 1 < TT)
                mp[(size_t)row * UU + u] = xp_all[((size_t)b * TT + t + 1) * UU + u];
        }
    }
}

// ---------------- host launcher ----------------
extern "C" void kernel_launch(void* const* d_in, const int* in_sizes, int n_in,
                              void* d_out, int out_size, void* d_ws, size_t ws_size,
                              hipStream_t stream)
{
    const float* x    = (const float*)d_in[0];   // [32,128,1024]
    const float* Wi   = (const float*)d_in[1];   // [1024,1024]
    const float* bi   = (const float*)d_in[2];   // [1024]
    const float* Wg   = (const float*)d_in[3];   // [1024,2048]
    const float* Wr   = (const float*)d_in[4];   // [1024,2048]
    const float* br   = (const float*)d_in[5];   // [2048]
    const float* Wa   = (const float*)d_in[6];   // [1024,3072]
    const float* ba   = (const float*)d_in[7];   // [3072]
    const float* Wm   = (const float*)d_in[8];   // [1024,2048]
    const float* bm   = (const float*)d_in[9];   // [2048]
    const float* gam  = (const float*)d_in[10];  // [2048]
    const float* bet  = (const float*)d_in[11];  // [2048]
    const float* Wrel = (const float*)d_in[12];  // [1024,1024]
    float* out = (float*)d_out;

    float* ws = (float*)d_ws;
    float* xp_all = ws;                                   // [4096,1024]
    float* gx_all = xp_all + (size_t)BB * TT * UU;        // [4096,2048]
    float* tab    = gx_all + (size_t)BB * TT * 2048;      // [17,1024]
    float* rproj  = tab + (size_t)RR * UU;                // [17,1024]
    float* mp     = rproj + (size_t)RR * UU;              // [288,1024]
    float* qkvg   = mp + (size_t)BB * LL * UU;            // [288,5120]
    float* a1     = qkvg + (size_t)BB * LL * 5120;        // [288,1024]
    float* h      = a1 + (size_t)BB * LL * UU;            // [288,1024]
    float* m2     = h + (size_t)BB * LL * UU;             // [288,1024]

    // ---- one-time prep ----
    relemb_kernel<<<RR, 256, 0, stream>>>(tab);
    gemm_f32<<<dim3(UU / BN, 1), 256, 0, stream>>>(tab, Wrel, rproj, RR, UU, UU);
    // xp_all = x @ Wi + bi
    gemm_big<<<dim3(UU / 128, (BB * TT) / 64), 256, 0, stream>>>(
        x, Wi, bi, xp_all, BB * TT, UU, UU, 0);
    // gx_all = x @ Wg
    gemm_big<<<dim3(2048 / 128, (BB * TT) / 64), 256, 0, stream>>>(
        x, Wg, nullptr, gx_all, BB * TT, 2048, UU, 0);
    init_mp<<<BB * LL, 256, 0, stream>>>(xp_all, mp);

    // ---- sequential scan ----
    for (int t = 0; t < TT; ++t) {
        // qkvg = mp @ [Wa|Wr] + [ba|br]
        gemm_qkvg<<<dim3(40, 5), 256, 0, stream>>>(mp, Wa, ba, Wr, br, qkvg);
        attn_ln<<<BB, 512, 0, stream>>>(qkvg, rproj, mp, gam, bet, a1);
        // h = gelu(a1 @ Wm[:, :U] + bm[:U])
        gemm_small<<<dim3(UU / 64, (BB * LL) / 32), 256, 0, stream>>>(
            a1, Wm, bm, h, BB * LL, UU, UU, 2048, 1);
        // m2 = h @ Wm[:, U:] + bm[U:]
        gemm_small<<<dim3(UU / 64, (BB * LL) / 32), 256, 0, stream>>>(
            h, Wm + 1024, bm + 1024, m2, BB * LL, UU, UU, 2048, 0);
        finalize_step<<<BB * LL, 256, 0, stream>>>(a1, m2, qkvg, gx_all, xp_all,
                                                   gam, bet, mp, out, t);
    }
}